// Round 15
// baseline (81760.980 us; speedup 1.0000x reference)
//
#include <hip/hip_runtime.h>
#include <stdint.h>

#define B_ 64
#define T_ 1024
#define I_ 128
#define H_ 512
#define O_ 64

typedef __attribute__((ext_vector_type(8))) short bf16x8;
typedef __attribute__((ext_vector_type(4))) float f32x4;
typedef unsigned short u16;
typedef unsigned int u32;
typedef unsigned long long u64;

struct Q2 { u64 a, b; };

__device__ __forceinline__ u16 f2bf(float f) {
  unsigned int u = __builtin_bit_cast(unsigned int, f);
  u += 0x7FFFu + ((u >> 16) & 1u);
  return (u16)(u >> 16);
}
__device__ __forceinline__ float bf2f(u16 h) {
  unsigned int u = ((unsigned int)h) << 16;
  return __builtin_bit_cast(float, u);
}

// ---------- fp32 -> (hi, lo) bf16 split ----------
__global__ void split_kernel(const float* __restrict__ src,
                             u16* __restrict__ hi, u16* __restrict__ lo, int n) {
  int i = blockIdx.x * 256 + threadIdx.x;
  if (i >= n) return;
  float f = src[i];
  u16 h = f2bf(f);
  hi[i] = h;
  lo[i] = f2bf(f - bf2f(h));
}

// x [B][T][I] fp32 -> xhi/xlo [T*B][I] (row r = t*B + b)
__global__ void xsplit_kernel(const float* __restrict__ x,
                              u16* __restrict__ hi, u16* __restrict__ lo) {
  int idx = blockIdx.x * 256 + threadIdx.x;  // over T*B*I
  int i = idx & (I_ - 1);
  int b = (idx >> 7) & (B_ - 1);
  int t = idx >> 13;
  float f = x[(((size_t)b << 10) | t) * I_ + i];
  u16 h = f2bf(f);
  hi[idx] = h;
  lo[idx] = f2bf(f - bf2f(h));
}

// debug sentinel
__global__ void sentinel_kernel(float* __restrict__ out, float v, int n) {
  int i = blockIdx.x * 256 + threadIdx.x;
  if (i < n) out[i] = v;
}

// ---------- projection GEMM (validated r2-r7) ----------
template <int K, bool ALO>
__global__ __launch_bounds__(256) void proj_gemm(
    const u16* __restrict__ Ahi, const u16* __restrict__ Alo,
    const u16* __restrict__ Whi, const u16* __restrict__ Wlo,
    const float* __restrict__ bih, const float* __restrict__ bhh,
    float* __restrict__ xp) {
  __shared__ u16 lhs[2][128 * 72];
  const int tid = threadIdx.x;
  const int w = tid >> 6, l = tid & 63;
  const int r15 = l & 15, g4 = l >> 4;
  const int Mbase = blockIdx.x * 128;
  const int Nbase = blockIdx.y * 128;
  f32x4 acc[2][8];
#pragma unroll
  for (int bt = 0; bt < 2; ++bt)
#pragma unroll
    for (int ct = 0; ct < 8; ++ct) acc[bt][ct] = (f32x4){0.f, 0.f, 0.f, 0.f};

  for (int kc = 0; kc < K; kc += 64) {
    __syncthreads();
#pragma unroll
    for (int i = 0; i < 4; ++i) {
      int e = i * 256 + tid;
      int c = e >> 3, kg = (e & 7) * 8;
      *(uint4*)&lhs[0][c * 72 + kg] =
          *(const uint4*)(Whi + (size_t)(Nbase + c) * K + kc + kg);
      *(uint4*)&lhs[1][c * 72 + kg] =
          *(const uint4*)(Wlo + (size_t)(Nbase + c) * K + kc + kg);
    }
    __syncthreads();
#pragma unroll
    for (int kt = 0; kt < 2; ++kt) {
      bf16x8 ah[2], al[2];
#pragma unroll
      for (int bt = 0; bt < 2; ++bt) {
        int row = Mbase + w * 32 + bt * 16 + r15;
        int koff = kc + kt * 32 + g4 * 8;
        ah[bt] = *(const bf16x8*)(Ahi + (size_t)row * K + koff);
        if (ALO) al[bt] = *(const bf16x8*)(Alo + (size_t)row * K + koff);
      }
#pragma unroll
      for (int ct = 0; ct < 8; ++ct) {
        int lo_off = (ct * 16 + r15) * 72 + kt * 32 + g4 * 8;
        bf16x8 bh = *(const bf16x8*)&lhs[0][lo_off];
        bf16x8 bl = *(const bf16x8*)&lhs[1][lo_off];
#pragma unroll
        for (int bt = 0; bt < 2; ++bt) {
          acc[bt][ct] = __builtin_amdgcn_mfma_f32_16x16x32_bf16(ah[bt], bh, acc[bt][ct], 0, 0, 0);
          acc[bt][ct] = __builtin_amdgcn_mfma_f32_16x16x32_bf16(ah[bt], bl, acc[bt][ct], 0, 0, 0);
          if (ALO)
            acc[bt][ct] = __builtin_amdgcn_mfma_f32_16x16x32_bf16(al[bt], bh, acc[bt][ct], 0, 0, 0);
        }
      }
    }
  }
#pragma unroll
  for (int ct = 0; ct < 8; ++ct) {
    int col = Nbase + ct * 16 + r15;
    float bc = bih[col] + bhh[col];
#pragma unroll
    for (int bt = 0; bt < 2; ++bt) {
#pragma unroll
      for (int j = 0; j < 4; ++j) {
        int row = Mbase + w * 32 + bt * 16 + g4 * 4 + j;
        xp[(size_t)row * H_ + col] = acc[bt][ct][j] + bc;
      }
    }
  }
}

// ---------- recurrent scan: ONE WG per batch-group, W in registers ----------
// grid = 4 WGs x 1024 thr (16 waves). NO cross-WG communication at all.
// Wave w: jg = w>>1 (64 j-rows), kh = w&1 (k-half of 256). W_hh slice
// (64j x 256k, hi+lo) resident in 256 VGPRs/wave (volatile-pinned).
// h lives in LDS double-buffered stage (r7-validated layout: 16 batch rows x
// 1024B k-bytes, 16B-chunk XOR swizzle ((row&7)<<4)), hi plane + lo plane.
// Per step: [A] all waves MFMA their (jg,kh) partial into 4 acc chains
//           [B] kh=1 waves write partials to LDS; barrier
//           [C] kh=0 waves: z = accA + accB + xp(t); tanh; split hi/lo;
//               write stage[next] + y (global, plain stores) + hn at t=T-1;
//               barrier.
// xp is the precomputed (validated proj_gemm) projection; layers run serially.
__global__ __launch_bounds__(1024, 1) void scan4_kernel(
    const u16* __restrict__ whh_hi, const u16* __restrict__ whh_lo,
    const float* __restrict__ xp, const float* __restrict__ h0l,
    u16* __restrict__ yhi, float* __restrict__ hn_out) {
  __shared__ __align__(16) char lds[98304];  // [0,32K) stage0 [32K,64K) stage1 [64K,96K) partials
  const int tid = threadIdx.x;
  const int l = tid & 63, w = tid >> 6;
  const int r15 = l & 15, g4 = l >> 4;
  const int jg = w >> 1, kh = w & 1;
  const int j0 = jg * 64;
  const int bb = blockIdx.x * 16;
  const int rxr = (r15 & 7) << 4;

  // --- W_hh slice -> registers (256 VGPRs), pinned against rematerialization
  bf16x8 wh[4][8], wl[4][8];
#pragma unroll
  for (int jt = 0; jt < 4; ++jt) {
    const size_t wr = (size_t)(j0 + jt * 16 + r15) * H_ + kh * 256 + g4 * 8;
#pragma unroll
    for (int kt = 0; kt < 8; ++kt) {
      wh[jt][kt] = *(const bf16x8*)(whh_hi + wr + kt * 32);
      wl[jt][kt] = *(const bf16x8*)(whh_lo + wr + kt * 32);
    }
  }
#pragma unroll
  for (int jt = 0; jt < 4; ++jt)
#pragma unroll
    for (int kt = 0; kt < 8; ++kt)
      asm volatile("" : "+v"(wh[jt][kt]), "+v"(wl[jt][kt]));

  // --- h0 -> stage[0] (split + swizzled); thread = (row=tid>>6, chunk=tid&63)
  {
    const int row = tid >> 6, cc = tid & 63;
    const float* src = h0l + (size_t)(bb + row) * H_ + cc * 8;
    u64 w0 = 0, w1 = 0, q0 = 0, q1 = 0;
#pragma unroll
    for (int i = 0; i < 4; ++i) {
      float f = src[i];
      u16 h = f2bf(f);
      w0 |= (u64)h << (16 * i);
      q0 |= (u64)f2bf(f - bf2f(h)) << (16 * i);
      float g = src[4 + i];
      u16 h2 = f2bf(g);
      w1 |= (u64)h2 << (16 * i);
      q1 |= (u64)f2bf(g - bf2f(h2)) << (16 * i);
    }
    int dst = row * 1024 + ((cc * 16) ^ ((row & 7) << 4));
    *(uint4*)(lds + dst) = __builtin_bit_cast(uint4, Q2{w0, w1});
    *(uint4*)(lds + 16384 + dst) = __builtin_bit_cast(uint4, Q2{q0, q1});
  }
  __syncthreads();

  const float* xpbase = xp + (size_t)(bb + r15) * H_ + j0 + g4 * 4;
  f32x4 xpv[4];

  for (int t = 0; t < T_; ++t) {
    char* cur = lds + (t & 1) * 32768;
    char* nxt = lds + ((t + 1) & 1) * 32768;
    // xp(t) prefetch for the consumers (lands during phase A)
    if (kh == 0) {
      const float* xr = xpbase + (size_t)t * (B_ * H_);
#pragma unroll
      for (int jt = 0; jt < 4; ++jt) xpv[jt] = *(const f32x4*)(xr + jt * 16);
    }
    // --- phase A: MFMA partials (W resident; h frags from LDS)
    f32x4 a[4];
#pragma unroll
    for (int jt = 0; jt < 4; ++jt) a[jt] = (f32x4){0.f, 0.f, 0.f, 0.f};
#pragma unroll
    for (int kt = 0; kt < 8; ++kt) {
      int kb = ((kh * 8 + kt) * 64 + g4 * 16) ^ rxr;
      bf16x8 hv = *(const bf16x8*)(cur + r15 * 1024 + kb);
      bf16x8 lv = *(const bf16x8*)(cur + 16384 + r15 * 1024 + kb);
#pragma unroll
      for (int jt = 0; jt < 4; ++jt)
        a[jt] = __builtin_amdgcn_mfma_f32_16x16x32_bf16(wh[jt][kt], hv, a[jt], 0, 0, 0);
#pragma unroll
      for (int jt = 0; jt < 4; ++jt)
        a[jt] = __builtin_amdgcn_mfma_f32_16x16x32_bf16(wl[jt][kt], hv, a[jt], 0, 0, 0);
#pragma unroll
      for (int jt = 0; jt < 4; ++jt)
        a[jt] = __builtin_amdgcn_mfma_f32_16x16x32_bf16(wh[jt][kt], lv, a[jt], 0, 0, 0);
    }
    // --- phase B: kh=1 writes partials (part[jg][jt][lane], 16B/lane: conflict-free)
    if (kh == 1) {
#pragma unroll
      for (int jt = 0; jt < 4; ++jt)
        *(f32x4*)(lds + 65536 + jg * 4096 + jt * 1024 + l * 16) = a[jt];
    }
    __syncthreads();
    // --- phase C: kh=0 reduces, tanh, writes stage[next] + y + hn
    if (kh == 0) {
#pragma unroll
      for (int jt = 0; jt < 4; ++jt) {
        f32x4 pv = *(const f32x4*)(lds + 65536 + jg * 4096 + jt * 1024 + l * 16);
        f32x4 z = a[jt] + pv + xpv[jt];
        u64 hip = 0, lop = 0;
        f32x4 vv;
#pragma unroll
        for (int r = 0; r < 4; ++r) {
          float e = __expf(2.0f * z[r]);
          float v = 1.0f - 2.0f * __builtin_amdgcn_rcpf(e + 1.0f);
          vv[r] = v;
          u16 hh = f2bf(v);
          hip |= (u64)hh << (16 * r);
          lop |= (u64)f2bf(v - bf2f(hh)) << (16 * r);
        }
        if (t < T_ - 1) {
          int jb = (j0 * 2 + jt * 32 + g4 * 8) ^ rxr;  // byte off in row (8B aligned)
          *(u64*)(nxt + r15 * 1024 + jb) = hip;
          *(u64*)(nxt + 16384 + r15 * 1024 + jb) = lop;
        }
        *(u64*)(yhi + ((size_t)t * B_ + bb + r15) * H_ + j0 + jt * 16 + g4 * 4) = hip;
        if (t == T_ - 1)
          *(f32x4*)(hn_out + (size_t)(bb + r15) * H_ + j0 + jt * 16 + g4 * 4) = vv;
      }
    }
    __syncthreads();
  }
}

// ---------- final FC + sigmoid ----------
__global__ __launch_bounds__(64) void fc_kernel(const float* __restrict__ hn2,
                                                const float* __restrict__ wfc,
                                                const float* __restrict__ bfc,
                                                float* __restrict__ out) {
  int b = blockIdx.x, o = threadIdx.x;
  __shared__ float hs[H_];
  for (int i = o; i < H_; i += 64) hs[i] = hn2[(size_t)b * H_ + i];
  __syncthreads();
  float acc = bfc[o];
#pragma unroll 4
  for (int k = 0; k < H_; k += 4) {
    float4 wv = *(const float4*)(wfc + (size_t)o * H_ + k);
    acc += hs[k] * wv.x + hs[k + 1] * wv.y + hs[k + 2] * wv.z + hs[k + 3] * wv.w;
  }
  out[b * O_ + o] = 1.f / (1.f + expf(-acc));
}

extern "C" void kernel_launch(void* const* d_in, const int* in_sizes, int n_in,
                              void* d_out, int out_size, void* d_ws, size_t ws_size,
                              hipStream_t stream) {
  (void)in_sizes; (void)n_in; (void)out_size;
  const float* x = (const float*)d_in[0];
  const float* h0 = (const float*)d_in[1];
  const float* w_ih[3] = {(const float*)d_in[2], (const float*)d_in[6], (const float*)d_in[10]};
  const float* w_hh[3] = {(const float*)d_in[3], (const float*)d_in[7], (const float*)d_in[11]};
  const float* b_ih[3] = {(const float*)d_in[4], (const float*)d_in[8], (const float*)d_in[12]};
  const float* b_hh[3] = {(const float*)d_in[5], (const float*)d_in[9], (const float*)d_in[13]};
  const float* w_fc = (const float*)d_in[14];
  const float* b_fc = (const float*)d_in[15];
  float* out = (float*)d_out;
  float* hn = out + B_ * O_;

  char* p = (char*)d_ws;
  auto carve = [&](size_t bytes) {
    char* r = p;
    p += (bytes + 255) & ~(size_t)255;
    return r;
  };
  float* xp = (float*)carve((size_t)T_ * B_ * H_ * 4);  // 128 MiB
  u16* yhi = (u16*)carve((size_t)T_ * B_ * H_ * 2);     // 64 MiB
  u16 *whhh[3], *whhl[3], *wihh[3], *wihl[3];
  for (int l = 0; l < 3; ++l) {
    whhh[l] = (u16*)carve((size_t)H_ * H_ * 2);
    whhl[l] = (u16*)carve((size_t)H_ * H_ * 2);
    int kin = (l == 0) ? I_ : H_;
    wihh[l] = (u16*)carve((size_t)H_ * kin * 2);
    wihl[l] = (u16*)carve((size_t)H_ * kin * 2);
  }
  size_t required = (size_t)(p - (char*)d_ws);
  if (required > ws_size) {
    int n = B_ * O_ + 3 * B_ * H_;
    sentinel_kernel<<<(n + 255) / 256, 256, 0, stream>>>(out, (float)(ws_size >> 20), n);
    return;
  }
  // x-split aliases the yhi region (dead before scan-0 writes yhi)
  u16* xhi = yhi;
  u16* xlo = yhi + (size_t)T_ * B_ * I_;

  for (int l = 0; l < 3; ++l) {
    split_kernel<<<H_ * H_ / 256, 256, 0, stream>>>(w_hh[l], whhh[l], whhl[l], H_ * H_);
    int kin = (l == 0) ? I_ : H_;
    split_kernel<<<H_ * kin / 256, 256, 0, stream>>>(w_ih[l], wihh[l], wihl[l], H_ * kin);
  }
  xsplit_kernel<<<T_ * B_ * I_ / 256, 256, 0, stream>>>(x, xhi, xlo);

  for (int l = 0; l < 3; ++l) {
    if (l == 0)
      proj_gemm<I_, true><<<dim3(T_ * B_ / 128, H_ / 128), 256, 0, stream>>>(
          xhi, xlo, wihh[0], wihl[0], b_ih[0], b_hh[0], xp);
    else
      proj_gemm<H_, false><<<dim3(T_ * B_ / 128, H_ / 128), 256, 0, stream>>>(
          yhi, yhi, wihh[l], wihl[l], b_ih[l], b_hh[l], xp);
    scan4_kernel<<<4, 1024, 0, stream>>>(whhh[l], whhl[l], xp,
                                         h0 + (size_t)l * B_ * H_, yhi,
                                         hn + (size_t)l * B_ * H_);
  }
  fc_kernel<<<B_, O_, 0, stream>>>(hn + 2 * (size_t)B_ * H_, w_fc, b_fc, out);
}

// Round 18
// 9018.670 us; speedup vs baseline: 9.0657x; 9.0657x over previous
//
#include <hip/hip_runtime.h>
#include <stdint.h>

#define B_ 64
#define T_ 1024
#define I_ 128
#define H_ 512
#define O_ 64
#define R16 16

typedef __attribute__((ext_vector_type(8))) short bf16x8;
typedef __attribute__((ext_vector_type(4))) float f32x4;
typedef unsigned short u16;
typedef unsigned int u32;
typedef unsigned long long u64;

struct Q2 { u64 a, b; };

__device__ __forceinline__ u16 f2bf(float f) {
  unsigned int u = __builtin_bit_cast(unsigned int, f);
  u += 0x7FFFu + ((u >> 16) & 1u);
  return (u16)(u >> 16);
}
__device__ __forceinline__ float bf2f(u16 h) {
  unsigned int u = ((unsigned int)h) << 16;
  return __builtin_bit_cast(float, u);
}
__device__ __forceinline__ u64 aload(const u64* p) {
  return __hip_atomic_load(p, __ATOMIC_RELAXED, __HIP_MEMORY_SCOPE_AGENT);
}
__device__ __forceinline__ void astore(u64* p, u64 v) {
  __hip_atomic_store(p, v, __ATOMIC_RELAXED, __HIP_MEMORY_SCOPE_AGENT);
}

// ---------- fp32 -> (hi, lo) bf16 split ----------
__global__ void split_kernel(const float* __restrict__ src,
                             u16* __restrict__ hi, u16* __restrict__ lo, int n) {
  int i = blockIdx.x * 256 + threadIdx.x;
  if (i >= n) return;
  float f = src[i];
  u16 h = f2bf(f);
  hi[i] = h;
  lo[i] = f2bf(f - bf2f(h));
}

// x [B][T][I] fp32 -> xhi/xlo [T*B][I] (row r = t*B + b)
__global__ void xsplit_kernel(const float* __restrict__ x,
                              u16* __restrict__ hi, u16* __restrict__ lo) {
  int idx = blockIdx.x * 256 + threadIdx.x;  // over T*B*I
  int i = idx & (I_ - 1);
  int b = (idx >> 7) & (B_ - 1);
  int t = idx >> 13;
  float f = x[(((size_t)b << 10) | t) * I_ + i];
  u16 h = f2bf(f);
  hi[idx] = h;
  lo[idx] = f2bf(f - bf2f(h));
}

// ring init: slot 0 <- h0 (split), slots 1..15 <- canary 0x7F80
__global__ void h0ring_kernel(const float* __restrict__ h0l,
                              u16* __restrict__ hxh, u16* __restrict__ hxl) {
  int idx = blockIdx.x * 256 + threadIdx.x;  // over R16*B*H
  int slot = idx >> 15;                      // B*H = 32768
  if (slot == 0) {
    float f = h0l[idx];
    u16 h = f2bf(f);
    hxh[idx] = h;
    hxl[idx] = f2bf(f - bf2f(h));
  } else {
    hxh[idx] = 0x7F80u;
    hxl[idx] = 0x7F80u;
  }
}

// debug sentinel
__global__ void sentinel_kernel(float* __restrict__ out, float v, int n) {
  int i = blockIdx.x * 256 + threadIdx.x;
  if (i < n) out[i] = v;
}

// ---------- projection GEMM (validated) ----------
template <int K, bool ALO>
__global__ __launch_bounds__(256) void proj_gemm(
    const u16* __restrict__ Ahi, const u16* __restrict__ Alo,
    const u16* __restrict__ Whi, const u16* __restrict__ Wlo,
    const float* __restrict__ bih, const float* __restrict__ bhh,
    float* __restrict__ xp) {
  __shared__ u16 lhs[2][128 * 72];
  const int tid = threadIdx.x;
  const int w = tid >> 6, l = tid & 63;
  const int r15 = l & 15, g4 = l >> 4;
  const int Mbase = blockIdx.x * 128;
  const int Nbase = blockIdx.y * 128;
  f32x4 acc[2][8];
#pragma unroll
  for (int bt = 0; bt < 2; ++bt)
#pragma unroll
    for (int ct = 0; ct < 8; ++ct) acc[bt][ct] = (f32x4){0.f, 0.f, 0.f, 0.f};

  for (int kc = 0; kc < K; kc += 64) {
    __syncthreads();
#pragma unroll
    for (int i = 0; i < 4; ++i) {
      int e = i * 256 + tid;
      int c = e >> 3, kg = (e & 7) * 8;
      *(uint4*)&lhs[0][c * 72 + kg] =
          *(const uint4*)(Whi + (size_t)(Nbase + c) * K + kc + kg);
      *(uint4*)&lhs[1][c * 72 + kg] =
          *(const uint4*)(Wlo + (size_t)(Nbase + c) * K + kc + kg);
    }
    __syncthreads();
#pragma unroll
    for (int kt = 0; kt < 2; ++kt) {
      bf16x8 ah[2], al[2];
#pragma unroll
      for (int bt = 0; bt < 2; ++bt) {
        int row = Mbase + w * 32 + bt * 16 + r15;
        int koff = kc + kt * 32 + g4 * 8;
        ah[bt] = *(const bf16x8*)(Ahi + (size_t)row * K + koff);
        if (ALO) al[bt] = *(const bf16x8*)(Alo + (size_t)row * K + koff);
      }
#pragma unroll
      for (int ct = 0; ct < 8; ++ct) {
        int lo_off = (ct * 16 + r15) * 72 + kt * 32 + g4 * 8;
        bf16x8 bh = *(const bf16x8*)&lhs[0][lo_off];
        bf16x8 bl = *(const bf16x8*)&lhs[1][lo_off];
#pragma unroll
        for (int bt = 0; bt < 2; ++bt) {
          acc[bt][ct] = __builtin_amdgcn_mfma_f32_16x16x32_bf16(ah[bt], bh, acc[bt][ct], 0, 0, 0);
          acc[bt][ct] = __builtin_amdgcn_mfma_f32_16x16x32_bf16(ah[bt], bl, acc[bt][ct], 0, 0, 0);
          if (ALO)
            acc[bt][ct] = __builtin_amdgcn_mfma_f32_16x16x32_bf16(al[bt], bh, acc[bt][ct], 0, 0, 0);
        }
      }
    }
  }
#pragma unroll
  for (int ct = 0; ct < 8; ++ct) {
    int col = Nbase + ct * 16 + r15;
    float bc = bih[col] + bhh[col];
#pragma unroll
    for (int bt = 0; bt < 2; ++bt) {
#pragma unroll
      for (int j = 0; j < 4; ++j) {
        int row = Mbase + w * 32 + bt * 16 + g4 * 4 + j;
        xp[(size_t)row * H_ + col] = acc[bt][ct][j] + bc;
      }
    }
  }
}

// ---------- recurrent scan: 64 WGs x 2 waves; LDS-staged canary exchange ----------
// r5 kernel verbatim (PASSED at 9,046us total; protocol class 5-for-5 reliable).
// WG bx: bg = bx>>4 (16 batch rows), sub = bx&15. Wave w: j0 = (sub*2+w)*16.
// hx ring [16][64][512] planar hi/lo bf16; relaxed agent u64 atomics only.
// Per step: coop poll-load 32KB (canary 0x7F80 top-u16, per-thread spin)
// -> ds_write (XOR-swizzled, double-buffered) -> barrier -> MFMA -> tanh -> stores.
// Scrub re-canaries slot (t+9) (unique writer; >=8 vmcnt drains before refill).
__global__ __launch_bounds__(128, 1) void scan_kernel(
    const u16* __restrict__ whh_hi, const u16* __restrict__ whh_lo,
    const float* __restrict__ xp,
    u16* __restrict__ yhi,
    u16* __restrict__ hxh, u16* __restrict__ hxl,
    float* __restrict__ hn_out) {
  __shared__ char lds[2][32768];  // [buf][hi 16x1024B | lo 16x1024B]
  const int tid = threadIdx.x;
  const int l = tid & 63, w = tid >> 6;
  const int bg = blockIdx.x >> 4, sub = blockIdx.x & 15;
  const int r15 = l & 15, g4 = l >> 4;
  const int j0 = (sub * 2 + w) * 16;
  const int bb = bg * 16;

  // W_hh A-fragments pinned in VGPRs (128)
  bf16x8 wh[16], wl[16];
  const size_t wrow = (size_t)(j0 + r15) * H_;
#pragma unroll
  for (int kt = 0; kt < 16; ++kt) {
    wh[kt] = *(const bf16x8*)(whh_hi + wrow + kt * 32 + g4 * 8);
    wl[kt] = *(const bf16x8*)(whh_lo + wrow + kt * 32 + g4 * 8);
    asm volatile("" : "+v"(wh[kt]), "+v"(wl[kt]));
  }

  // stage mapping: thread -> (row sr, chunk sc); 16B chunks strided 128B
  const int sr = tid >> 3, sc = tid & 7;
  const int sxr = (sr & 7) << 4;       // write-side XOR
  const int rxr = (r15 & 7) << 4;      // read-side XOR
  const int rdoff = r15 * 1024;

  const float* xpp = xp + (size_t)(bb + r15) * H_ + j0 + g4 * 4;
  f32x4 xpv = *(const f32x4*)xpp;  // t = 0

  for (int t = 0; t < T_; ++t) {
    const int slot = t & (R16 - 1), slot1 = (t + 1) & (R16 - 1);
    // --- cooperative poll-load of h[bb..bb+16][0..512] hi+lo (own 256B per thread)
    const u64* gh = (const u64*)(hxh + ((size_t)slot * B_ + bb + sr) * H_);
    const u64* gl = (const u64*)(hxl + ((size_t)slot * B_ + bb + sr) * H_);
    u64 vh[16], vl[16];
    for (;;) {
#pragma unroll
      for (int i = 0; i < 8; ++i) {
        int u = sc * 2 + i * 16;
        vh[2 * i] = aload(gh + u);
        vh[2 * i + 1] = aload(gh + u + 1);
        vl[2 * i] = aload(gl + u);
        vl[2 * i + 1] = aload(gl + u + 1);
      }
      bool ok = true;
#pragma unroll
      for (int i = 0; i < 16; ++i)
        ok = ok && ((vh[i] >> 48) != 0x7F80ull) && ((vl[i] >> 48) != 0x7F80ull);
      if (ok) break;
      __builtin_amdgcn_s_sleep(1);
    }
    char* base = lds[t & 1];
#pragma unroll
    for (int i = 0; i < 8; ++i) {
      int kb = (sc * 16 + i * 128) ^ sxr;
      *(uint4*)(base + sr * 1024 + kb) = __builtin_bit_cast(uint4, Q2{vh[2 * i], vh[2 * i + 1]});
      *(uint4*)(base + 16384 + sr * 1024 + kb) =
          __builtin_bit_cast(uint4, Q2{vl[2 * i], vl[2 * i + 1]});
    }
    __syncthreads();
    // --- compute: 16 kt x 3 split MFMAs, 4 independent chains
    f32x4 a0 = xpv, a1 = {0.f, 0.f, 0.f, 0.f}, a2 = a1, a3 = a1;
#pragma unroll
    for (int kt = 0; kt < 16; ++kt) {
      int kb = (kt * 64 + g4 * 16) ^ rxr;
      bf16x8 hv = *(const bf16x8*)(base + rdoff + kb);
      bf16x8 lv = *(const bf16x8*)(base + 16384 + rdoff + kb);
      f32x4* ac = (kt & 3) == 0 ? &a0 : (kt & 3) == 1 ? &a1 : (kt & 3) == 2 ? &a2 : &a3;
      *ac = __builtin_amdgcn_mfma_f32_16x16x32_bf16(wh[kt], hv, *ac, 0, 0, 0);
      *ac = __builtin_amdgcn_mfma_f32_16x16x32_bf16(wl[kt], hv, *ac, 0, 0, 0);
      *ac = __builtin_amdgcn_mfma_f32_16x16x32_bf16(wh[kt], lv, *ac, 0, 0, 0);
    }
    f32x4 s = (a0 + a1) + (a2 + a3);
    float v[4];
#pragma unroll
    for (int j = 0; j < 4; ++j) {
      float e = __expf(2.0f * s[j]);
      v[j] = 1.0f - 2.0f * __builtin_amdgcn_rcpf(e + 1.0f);
    }
    u64 hip = 0, lop = 0;
#pragma unroll
    for (int j = 0; j < 4; ++j) {
      u16 hh = f2bf(v[j]);
      u16 ll = f2bf(v[j] - bf2f(hh));
      hip |= (u64)hh << (16 * j);
      lop |= (u64)ll << (16 * j);
    }
    if (t < T_ - 1) {
      size_t so = ((size_t)slot1 * B_ + bb + r15) * (size_t)H_ + j0 + g4 * 4;  // u16 idx
      astore((u64*)hxh + (so >> 2), hip);
      astore((u64*)hxl + (so >> 2), lop);
      // scrub slot (t+9) at this lane's own fill addresses (unique writer)
      const int slotS = (t + 9) & (R16 - 1);
      size_t ss = ((size_t)slotS * B_ + bb + r15) * (size_t)H_ + j0 + g4 * 4;
      astore((u64*)hxh + (ss >> 2), 0x7F807F807F807F80ull);
      astore((u64*)hxl + (ss >> 2), 0x7F807F807F807F80ull);
    }
    *(u64*)(yhi + ((size_t)t * B_ + bb + r15) * H_ + j0 + g4 * 4) = hip;
    if (t == T_ - 1) {
      f32x4 hv4 = {v[0], v[1], v[2], v[3]};
      *(f32x4*)(hn_out + (size_t)(bb + r15) * H_ + j0 + g4 * 4) = hv4;
    } else {
      xpv = *(const f32x4*)(xpp + (size_t)(t + 1) * B_ * H_);  // prefetch next step
    }
  }
}

// ---------- final FC + sigmoid ----------
__global__ __launch_bounds__(64) void fc_kernel(const float* __restrict__ hn2,
                                                const float* __restrict__ wfc,
                                                const float* __restrict__ bfc,
                                                float* __restrict__ out) {
  int b = blockIdx.x, o = threadIdx.x;
  __shared__ float hs[H_];
  for (int i = o; i < H_; i += 64) hs[i] = hn2[(size_t)b * H_ + i];
  __syncthreads();
  float acc = bfc[o];
#pragma unroll 4
  for (int k = 0; k < H_; k += 4) {
    float4 wv = *(const float4*)(wfc + (size_t)o * H_ + k);
    acc += hs[k] * wv.x + hs[k + 1] * wv.y + hs[k + 2] * wv.z + hs[k + 3] * wv.w;
  }
  out[b * O_ + o] = 1.f / (1.f + expf(-acc));
}

extern "C" void kernel_launch(void* const* d_in, const int* in_sizes, int n_in,
                              void* d_out, int out_size, void* d_ws, size_t ws_size,
                              hipStream_t stream) {
  (void)in_sizes; (void)n_in; (void)out_size;
  const float* x = (const float*)d_in[0];
  const float* h0 = (const float*)d_in[1];
  const float* w_ih[3] = {(const float*)d_in[2], (const float*)d_in[6], (const float*)d_in[10]};
  const float* w_hh[3] = {(const float*)d_in[3], (const float*)d_in[7], (const float*)d_in[11]};
  const float* b_ih[3] = {(const float*)d_in[4], (const float*)d_in[8], (const float*)d_in[12]};
  const float* b_hh[3] = {(const float*)d_in[5], (const float*)d_in[9], (const float*)d_in[13]};
  const float* w_fc = (const float*)d_in[14];
  const float* b_fc = (const float*)d_in[15];
  float* out = (float*)d_out;
  float* hn = out + B_ * O_;

  char* p = (char*)d_ws;
  auto carve = [&](size_t bytes) {
    char* r = p;
    p += (bytes + 255) & ~(size_t)255;
    return r;
  };
  float* xp = (float*)carve((size_t)T_ * B_ * H_ * 4);   // 128 MiB
  u16* yhi = (u16*)carve((size_t)T_ * B_ * H_ * 2);      // 64 MiB
  u16* hxh = (u16*)carve((size_t)R16 * B_ * H_ * 2);     // 1 MiB
  u16* hxl = (u16*)carve((size_t)R16 * B_ * H_ * 2);     // 1 MiB
  u16 *whhh[3], *whhl[3], *wihh[3], *wihl[3];
  for (int l = 0; l < 3; ++l) {
    whhh[l] = (u16*)carve((size_t)H_ * H_ * 2);
    whhl[l] = (u16*)carve((size_t)H_ * H_ * 2);
    int kin = (l == 0) ? I_ : H_;
    wihh[l] = (u16*)carve((size_t)H_ * kin * 2);
    wihl[l] = (u16*)carve((size_t)H_ * kin * 2);
  }
  size_t required = (size_t)(p - (char*)d_ws);
  if (required > ws_size) {
    int n = B_ * O_ + 3 * B_ * H_;
    sentinel_kernel<<<(n + 255) / 256, 256, 0, stream>>>(out, (float)(ws_size >> 20), n);
    return;
  }
  // x-split aliases the yhi region (dead before scan-0 writes yhi)
  u16* xhi = yhi;
  u16* xlo = yhi + (size_t)T_ * B_ * I_;

  for (int l = 0; l < 3; ++l) {
    split_kernel<<<H_ * H_ / 256, 256, 0, stream>>>(w_hh[l], whhh[l], whhl[l], H_ * H_);
    int kin = (l == 0) ? I_ : H_;
    split_kernel<<<H_ * kin / 256, 256, 0, stream>>>(w_ih[l], wihh[l], wihl[l], H_ * kin);
  }
  xsplit_kernel<<<T_ * B_ * I_ / 256, 256, 0, stream>>>(x, xhi, xlo);

  for (int l = 0; l < 3; ++l) {
    h0ring_kernel<<<R16 * B_ * H_ / 256, 256, 0, stream>>>(h0 + (size_t)l * B_ * H_, hxh, hxl);
    if (l == 0)
      proj_gemm<I_, true><<<dim3(T_ * B_ / 128, H_ / 128), 256, 0, stream>>>(
          xhi, xlo, wihh[0], wihl[0], b_ih[0], b_hh[0], xp);
    else
      proj_gemm<H_, false><<<dim3(T_ * B_ / 128, H_ / 128), 256, 0, stream>>>(
          yhi, yhi, wihh[l], wihl[l], b_ih[l], b_hh[l], xp);
    scan_kernel<<<64, 128, 0, stream>>>(whhh[l], whhl[l], xp, yhi, hxh, hxl,
                                        hn + (size_t)l * B_ * H_);
  }
  fc_kernel<<<B_, O_, 0, stream>>>(hn + 2 * (size_t)B_ * H_, w_fc, b_fc, out);
}